// Round 2
// baseline (120.384 us; speedup 1.0000x reference)
//
#include <hip/hip_runtime.h>

#define BB 8
#define NN 1024
#define DIN 64
#define DOUT 64
#define EMB 16
#define DPC 16

typedef __attribute__((ext_vector_type(8))) short bf16x8;
typedef __attribute__((ext_vector_type(4))) float f32x4;

__device__ inline unsigned short f2bf(float f) {
    unsigned u = __float_as_uint(f);
    u += 0x7fffu + ((u >> 16) & 1u);      // RNE (finite only)
    return (unsigned short)(u >> 16);
}

// =======================================================================
// k_front: heterogeneous kernel.
//   blocks [0,256)     : z3   — Z, Sub (bf16 exp matrix), xzT
//   blocks [256,1280)  : sim  — sim_bf = bf16(softmax_rows(relu(E E^T)))
//   blocks [1280,1296) : pack — WPT[d*64+o][k*64+i] = bf16(wp[d][k][i][o])
// (wgen/W2 removed: the output contraction now recomputes from WPT, which
//  is 256 KB and L2-resident, instead of streaming 32 MiB of W2.)
// =======================================================================
__global__ __launch_bounds__(256) void k_front(const float* __restrict__ E,
                                               const float* __restrict__ pa,
                                               const float* __restrict__ x,
                                               const float* __restrict__ wp,
                                               unsigned short* __restrict__ sim_bf,
                                               unsigned short* __restrict__ Sub,
                                               unsigned short* __restrict__ xzT,
                                               unsigned short* __restrict__ WPT) {
    __shared__ __align__(16) char smem[36096];
    const int bid = blockIdx.x;
    const int tid = threadIdx.x;

    if (bid < 256) {
        // ---------------- z3: Z + Sub + xzT ----------------
        const int b = bid >> 5, c0 = (bid & 31) * 32;
        float* pa_l  = (float*)smem;                 // 512*16 f = 32 KB (later reused as xl)
        float* myp   = (float*)(smem + 32768);       // 32*16 f  = 2 KB
        float* zpart = (float*)(smem + 34816);       // 8*32 f   = 1 KB
        float* invZ  = (float*)(smem + 35840);       // 32 f

        if (tid < 128)
            ((float4*)myp)[tid] = *(const float4*)&pa[((size_t)b*NN + c0)*DPC + tid*4];
        __syncthreads();

        const int cs = tid & 31, jq = tid >> 5;
        float myc[DPC];
        #pragma unroll
        for (int p4 = 0; p4 < 4; ++p4) {
            float4 t = *(const float4*)&myp[cs*DPC + p4*4];
            myc[p4*4+0] = t.x; myc[p4*4+1] = t.y; myc[p4*4+2] = t.z; myc[p4*4+3] = t.w;
        }

        float part = 0.0f;
        for (int h = 0; h < 2; ++h) {
            __syncthreads();
            for (int i = tid; i < 512*DPC/4; i += 256)
                ((float4*)pa_l)[i] = ((const float4*)(pa + ((size_t)b*NN + h*512)*DPC))[i];
            __syncthreads();
            unsigned short* subrow = Sub + ((size_t)b*NN + (c0 + cs))*NN + h*512 + jq*64;
            for (int j4 = 0; j4 < 16; ++j4) {
                float e[4];
                #pragma unroll
                for (int t = 0; t < 4; ++t) {
                    int jj = jq*64 + j4*4 + t;
                    float s = 0.0f;
                    #pragma unroll
                    for (int p4 = 0; p4 < 4; ++p4) {
                        float4 q = *(const float4*)&pa_l[jj*DPC + p4*4];
                        s += fabsf(myc[p4*4+0]-q.x) + fabsf(myc[p4*4+1]-q.y)
                           + fabsf(myc[p4*4+2]-q.z) + fabsf(myc[p4*4+3]-q.w);
                    }
                    e[t] = __expf(-s);
                }
                part += e[0] + e[1] + e[2] + e[3];
                *(ushort4*)&subrow[j4*4] =
                    make_ushort4(f2bf(e[0]), f2bf(e[1]), f2bf(e[2]), f2bf(e[3]));
            }
        }
        zpart[jq*32 + cs] = part;
        __syncthreads();
        // reuse pa_l as xl[32][65]
        float* xl = pa_l;
        #pragma unroll
        for (int i = 0; i < 8; ++i) {
            int l = i*256 + tid, d = l & 63, c = l >> 6;
            xl[c*65 + d] = x[((size_t)b*NN + c0 + c)*DIN + d];
        }
        if (tid < 32) {
            float z = 0.f;
            #pragma unroll
            for (int q = 0; q < 8; ++q) z += zpart[q*32 + tid];
            invZ[tid] = 1.0f / z;
        }
        __syncthreads();
        #pragma unroll
        for (int i = 0; i < 8; ++i) {
            int l = i*256 + tid, c = l & 31, d = l >> 5;
            xzT[((size_t)b*DIN + d)*NN + c0 + c] = f2bf(xl[c*65 + d] * invZ[c]);
        }
    } else if (bid < 1280) {
        // ---------------- sim ----------------
        const int i = bid - 256;
        const int lane = tid & 63, wave = tid >> 6;
        float* redw = (float*)smem;                  // 4 f

        float4 ei0 = *(const float4*)&E[i*EMB + 0];
        float4 ei1 = *(const float4*)&E[i*EMB + 4];
        float4 ei2 = *(const float4*)&E[i*EMB + 8];
        float4 ei3 = *(const float4*)&E[i*EMB + 12];

        float rv[4], tmax = -1e30f;
        #pragma unroll
        for (int k = 0; k < 4; ++k) {
            int j = tid + k*256;
            float4 a0 = *(const float4*)&E[j*EMB + 0];
            float4 a1 = *(const float4*)&E[j*EMB + 4];
            float4 a2 = *(const float4*)&E[j*EMB + 8];
            float4 a3 = *(const float4*)&E[j*EMB + 12];
            float s = ei0.x*a0.x + ei0.y*a0.y + ei0.z*a0.z + ei0.w*a0.w
                    + ei1.x*a1.x + ei1.y*a1.y + ei1.z*a1.z + ei1.w*a1.w
                    + ei2.x*a2.x + ei2.y*a2.y + ei2.z*a2.z + ei2.w*a2.w
                    + ei3.x*a3.x + ei3.y*a3.y + ei3.z*a3.z + ei3.w*a3.w;
            s = fmaxf(s, 0.0f);
            rv[k] = s; tmax = fmaxf(tmax, s);
        }
        #pragma unroll
        for (int off = 32; off > 0; off >>= 1) tmax = fmaxf(tmax, __shfl_xor(tmax, off));
        if (lane == 0) redw[wave] = tmax;
        __syncthreads();
        float rmax = fmaxf(fmaxf(redw[0], redw[1]), fmaxf(redw[2], redw[3]));
        __syncthreads();

        float ev[4], tsum = 0.f;
        #pragma unroll
        for (int k = 0; k < 4; ++k) { ev[k] = __expf(rv[k] - rmax); tsum += ev[k]; }
        #pragma unroll
        for (int off = 32; off > 0; off >>= 1) tsum += __shfl_xor(tsum, off);
        if (lane == 0) redw[wave] = tsum;
        __syncthreads();
        float inv = 1.0f / (redw[0] + redw[1] + redw[2] + redw[3]);
        #pragma unroll
        for (int k = 0; k < 4; ++k)
            sim_bf[(size_t)i*NN + tid + k*256] = f2bf(ev[k] * inv);
    } else {
        // ---------------- pack: WPT[col=d*64+o][ki=k*64+i] = bf16(wp[d][k][i][o]) ----------------
        const int d = bid - 1280;
        float* wpl = (float*)smem;                   // 8192 f = 32 KB
        const float* wsrc = wp + (size_t)d * 8192;
        for (int i = tid; i < 2048; i += 256)
            ((float4*)wpl)[i] = ((const float4*)wsrc)[i];
        __syncthreads();
        const int o = tid & 63, g = tid >> 6;        // g: i-quarter
        #pragma unroll
        for (int k = 0; k < 2; ++k) {
            unsigned short tmp[16];
            #pragma unroll
            for (int t = 0; t < 16; ++t)
                tmp[t] = f2bf(wpl[k*4096 + (g*16 + t)*64 + o]);
            unsigned short* dst = WPT + (size_t)(d*64 + o)*128 + k*64 + g*16;
            #pragma unroll
            for (int t4 = 0; t4 < 4; ++t4)
                *(ushort4*)&dst[t4*4] =
                    make_ushort4(tmp[t4*4], tmp[t4*4+1], tmp[t4*4+2], tmp[t4*4+3]);
        }
    }
}

// =======================================================================
// bf16 GEMM tile: C[16m x 64d] = A[16m x 1024k] * B^T[64d x 1024k]
// K-step 64, register prefetch, single LDS buffer. 4 waves: wave w owns
// d-cols w*16..w*16+15. Strides 72 give even bank spread for b128 ops.
// =======================================================================
#define ASTR 72
#define BSTR 72

__device__ inline void gemm_tile(const unsigned short* __restrict__ Arow,   // A[r][c] = Arow[r*NN+c]
                                 const unsigned short* __restrict__ Brow,   // B[d][c] = Brow[d*NN+c]
                                 unsigned short* A_l, unsigned short* B_l,
                                 int tid, f32x4& acc) {
    const int lane = tid & 63, wave = tid >> 6;
    const int q = lane >> 4, r = lane & 15;

    const int brow_ = tid >> 2, bch = (tid & 3) * 2;
    const int arow_ = tid >> 3, ach = tid & 7;

    uint4 pb0 = *(const uint4*)&Brow[(size_t)brow_*NN + (bch+0)*8];
    uint4 pb1 = *(const uint4*)&Brow[(size_t)brow_*NN + (bch+1)*8];
    uint4 pa0;
    if (tid < 128) pa0 = *(const uint4*)&Arow[(size_t)arow_*NN + ach*8];

    for (int kk = 0; kk < 16; ++kk) {
        __syncthreads();
        *(uint4*)&B_l[brow_*BSTR + (bch+0)*8] = pb0;
        *(uint4*)&B_l[brow_*BSTR + (bch+1)*8] = pb1;
        if (tid < 128) *(uint4*)&A_l[arow_*ASTR + ach*8] = pa0;
        __syncthreads();
        if (kk < 15) {
            int c1 = (kk + 1) * 64;
            pb0 = *(const uint4*)&Brow[(size_t)brow_*NN + c1 + (bch+0)*8];
            pb1 = *(const uint4*)&Brow[(size_t)brow_*NN + c1 + (bch+1)*8];
            if (tid < 128) pa0 = *(const uint4*)&Arow[(size_t)arow_*NN + c1 + ach*8];
        }
        bf16x8 a0 = *(const bf16x8*)&A_l[r*ASTR + q*8];
        bf16x8 b0 = *(const bf16x8*)&B_l[(wave*16 + r)*BSTR + q*8];
        acc = __builtin_amdgcn_mfma_f32_16x16x32_bf16(a0, b0, acc, 0, 0, 0);
        bf16x8 a1 = *(const bf16x8*)&A_l[r*ASTR + 32 + q*8];
        bf16x8 b1 = *(const bf16x8*)&B_l[(wave*16 + r)*BSTR + 32 + q*8];
        acc = __builtin_amdgcn_mfma_f32_16x16x32_bf16(a1, b1, acc, 0, 0, 0);
    }
}

// ---------------- k_sx4: sx = Sub(m-rows) @ xz ; emits sx_bf + sxT (both bf16) ----------------
__global__ __launch_bounds__(256) void k_sx4(const unsigned short* __restrict__ Sub,
                                             const unsigned short* __restrict__ xzT,
                                             unsigned short* __restrict__ sx_bf,
                                             unsigned short* __restrict__ sxT) {
    const int b = blockIdx.y, m0 = blockIdx.x * 16;
    const int tid = threadIdx.x, lane = tid & 63, wave = tid >> 6;
    __shared__ __align__(16) unsigned short A_l[16 * ASTR];
    __shared__ __align__(16) unsigned short B_l[64 * BSTR];

    f32x4 acc = {0.f, 0.f, 0.f, 0.f};
    gemm_tile(Sub + ((size_t)b*NN + m0)*NN, xzT + (size_t)b*DIN*NN, A_l, B_l, tid, acc);

    const int q = lane >> 4, r = lane & 15;
    const int d = wave*16 + r;
    const int mrow = m0 + q*4;
    unsigned short h0 = f2bf(acc[0]), h1 = f2bf(acc[1]), h2 = f2bf(acc[2]), h3 = f2bf(acc[3]);
    sx_bf[((size_t)b*NN + mrow + 0)*DIN + d] = h0;
    sx_bf[((size_t)b*NN + mrow + 1)*DIN + d] = h1;
    sx_bf[((size_t)b*NN + mrow + 2)*DIN + d] = h2;
    sx_bf[((size_t)b*NN + mrow + 3)*DIN + d] = h3;
    *(ushort4*)&sxT[((size_t)b*DIN + d)*NN + mrow] = make_ushort4(h0, h1, h2, h3);
}

// =======================================================================
// k_y_out: y = sim_bf(m-rows) @ sx (B from sxT), then WITHOUT round-tripping
// y through HBM:
//   P[row, d*64+o] = sum_ki [sx_bf | y][row,ki] * WPT[d*64+o][ki]   (MFMA, K=128)
//   out[row,o]     = sum_d E[n,d] * P[row,d*64+o] + sum_d E[n,d]*bp[d,o]
// WPT is 256 KB -> L2-resident; B-fragments are loaded straight from global.
// =======================================================================
#define S2 136          // A2 row stride (u16): 128 data + 8 pad
#define PSTR 65         // partials row stride (f32)

__global__ __launch_bounds__(256) void k_y_out(const unsigned short* __restrict__ sim_bf,
                                               const unsigned short* __restrict__ sxT,
                                               const unsigned short* __restrict__ sx_bf,
                                               const unsigned short* __restrict__ WPT,
                                               const float* __restrict__ E,
                                               const float* __restrict__ bp,
                                               float* __restrict__ out) {
    const int b = blockIdx.y, m0 = blockIdx.x * 16;
    const int tid = threadIdx.x, lane = tid & 63, wave = tid >> 6;
    __shared__ __align__(16) unsigned short A_l[16 * ASTR];
    __shared__ __align__(16) unsigned short B_l[64 * BSTR];
    __shared__ __align__(16) unsigned short A2[16 * S2];   // [row][ki]: 0..63 = sx, 64..127 = y
    __shared__ float E16[16 * EMB];                        // E rows m0..m0+15
    __shared__ float bpl[EMB * DOUT];                      // bias pool
    __shared__ float part[4 * 16 * PSTR];                  // per-wave d-partials

    // stage epilogue inputs early (ordered by the barriers inside gemm_tile)
    E16[tid] = E[(size_t)m0 * EMB + tid];                  // 256 contiguous f32
    ((float4*)bpl)[tid] = ((const float4*)bp)[tid];        // 1024 f32
    if (tid < 128) {                                       // sx half of A2 (already bf16)
        int row = tid >> 3, c8 = (tid & 7) * 8;
        *(uint4*)&A2[row*S2 + c8] =
            *(const uint4*)&sx_bf[((size_t)b*NN + m0 + row)*DIN + c8];
    }

    f32x4 acc = {0.f, 0.f, 0.f, 0.f};
    gemm_tile(sim_bf + (size_t)m0*NN, sxT + (size_t)b*DIN*NN, A_l, B_l, tid, acc);

    const int q = lane >> 4, r = lane & 15;
    // y half of A2: wave owns cols wave*16+r, rows q*4+reg
    #pragma unroll
    for (int reg = 0; reg < 4; ++reg)
        A2[(q*4 + reg)*S2 + 64 + wave*16 + r] = f2bf(acc[reg]);
    __syncthreads();

    // ---- P-GEMM: [16 x 128] @ [128 x 1024], wave w owns cols w*256..w*256+255 ----
    bf16x8 af[4];
    #pragma unroll
    for (int ks = 0; ks < 4; ++ks)
        af[ks] = *(const bf16x8*)&A2[r*S2 + ks*32 + q*8];

    f32x4 pacc[16];
    #pragma unroll
    for (int i = 0; i < 16; ++i) pacc[i] = (f32x4){0.f, 0.f, 0.f, 0.f};

    const unsigned short* wbase = WPT + ((size_t)(wave*256 + r))*128 + q*8;
    #pragma unroll
    for (int nfl = 0; nfl < 16; ++nfl) {
        const unsigned short* bb = wbase + (size_t)nfl * 16 * 128;
        #pragma unroll
        for (int ks = 0; ks < 4; ++ks) {
            bf16x8 bf_ = *(const bf16x8*)(bb + ks*32);
            pacc[nfl] = __builtin_amdgcn_mfma_f32_16x16x32_bf16(af[ks], bf_, pacc[nfl], 0, 0, 0);
        }
    }

    // ---- contract with E over this wave's 4 d-values ----
    // col = wave*256 + nfl*16 + r  ->  d = wave*4 + (nfl>>2), o = (nfl&3)*16 + r
    float po[4][4];
    #pragma unroll
    for (int reg = 0; reg < 4; ++reg)
        #pragma unroll
        for (int ohi = 0; ohi < 4; ++ohi) po[reg][ohi] = 0.f;
    #pragma unroll
    for (int nfl = 0; nfl < 16; ++nfl) {
        const int dd = nfl >> 2, ohi = nfl & 3;
        #pragma unroll
        for (int reg = 0; reg < 4; ++reg)
            po[reg][ohi] += E16[(q*4 + reg)*EMB + wave*4 + dd] * pacc[nfl][reg];
    }
    #pragma unroll
    for (int reg = 0; reg < 4; ++reg)
        #pragma unroll
        for (int ohi = 0; ohi < 4; ++ohi)
            part[wave*16*PSTR + (q*4 + reg)*PSTR + ohi*16 + r] = po[reg][ohi];
    __syncthreads();

    // ---- reduce 4 waves (4 d-groups each) + bias, write out ----
    {
        const int row = tid >> 4, o4 = (tid & 15) * 4;
        float4 res;
        #pragma unroll
        for (int j = 0; j < 4; ++j) {
            const int o = o4 + j;
            float s = part[0*16*PSTR + row*PSTR + o] + part[1*16*PSTR + row*PSTR + o]
                    + part[2*16*PSTR + row*PSTR + o] + part[3*16*PSTR + row*PSTR + o];
            float bsum = 0.f;
            #pragma unroll
            for (int d = 0; d < EMB; ++d)
                bsum += E16[row*EMB + d] * bpl[d*DOUT + o];
            ((float*)&res)[j] = s + bsum;
        }
        *(float4*)&out[((size_t)b*NN + m0 + row)*DOUT + o4] = res;
    }
}

extern "C" void kernel_launch(void* const* d_in, const int* in_sizes, int n_in,
                              void* d_out, int out_size, void* d_ws, size_t ws_size,
                              hipStream_t stream) {
    (void)in_sizes; (void)n_in; (void)out_size; (void)ws_size;
    const float* x  = (const float*)d_in[0];
    const float* E  = (const float*)d_in[1];
    const float* pa = (const float*)d_in[2];
    const float* wp = (const float*)d_in[3];
    const float* bp = (const float*)d_in[4];
    float* out = (float*)d_out;

    // ws layout (~21.3 MiB used)
    unsigned short* ws16   = (unsigned short*)d_ws;
    unsigned short* sim_bf = ws16;                       // 1,048,576 us (2 MiB)
    unsigned short* xzT    = sim_bf + (size_t)NN*NN;     //   524,288 us (1 MiB)
    unsigned short* sxT    = xzT + (size_t)BB*DIN*NN;    //   524,288 us (1 MiB)
    unsigned short* Sub    = sxT + (size_t)BB*DIN*NN;    // 8,388,608 us (16 MiB)
    unsigned short* sx_bf  = Sub + (size_t)BB*NN*NN;     //   524,288 us (1 MiB)
    unsigned short* WPT    = sx_bf + (size_t)BB*NN*DIN;  //   131,072 us (256 KiB)

    k_front<<<1296, 256, 0, stream>>>(E, pa, x, wp, sim_bf, Sub, xzT, WPT);
    k_sx4<<<dim3(64, BB), 256, 0, stream>>>(Sub, xzT, sx_bf, sxT);
    k_y_out<<<dim3(64, BB), 256, 0, stream>>>(sim_bf, sxT, sx_bf, WPT, E, bp, out);
}

// Round 3
// 115.037 us; speedup vs baseline: 1.0465x; 1.0465x over previous
//
#include <hip/hip_runtime.h>

#define BB 8
#define NN 1024
#define DIN 64
#define DOUT 64
#define EMB 16
#define DPC 16

typedef __attribute__((ext_vector_type(8))) short bf16x8;
typedef __attribute__((ext_vector_type(4))) float f32x4;

__device__ inline unsigned short f2bf(float f) {
    unsigned u = __float_as_uint(f);
    u += 0x7fffu + ((u >> 16) & 1u);      // RNE (finite only)
    return (unsigned short)(u >> 16);
}

// =======================================================================
// k_front: heterogeneous kernel.
//   blocks [0,256)     : z3   — Z, Sub (bf16 exp matrix), xzT
//   blocks [256,1280)  : sim  — sim_bf = bf16(softmax_rows(relu(E E^T)))
//   blocks [1280,1296) : pack — WPT[d*64+o][k*64+i] = bf16(wp[d][k][i][o])
// =======================================================================
__global__ __launch_bounds__(256) void k_front(const float* __restrict__ E,
                                               const float* __restrict__ pa,
                                               const float* __restrict__ x,
                                               const float* __restrict__ wp,
                                               unsigned short* __restrict__ sim_bf,
                                               unsigned short* __restrict__ Sub,
                                               unsigned short* __restrict__ xzT,
                                               unsigned short* __restrict__ WPT) {
    __shared__ __align__(16) char smem[36096];
    const int bid = blockIdx.x;
    const int tid = threadIdx.x;

    if (bid < 256) {
        // ---------------- z3: Z + Sub + xzT ----------------
        const int b = bid >> 5, c0 = (bid & 31) * 32;
        float* pa_l  = (float*)smem;                 // 512*16 f = 32 KB (later reused as xl)
        float* myp   = (float*)(smem + 32768);       // 32*16 f  = 2 KB
        float* zpart = (float*)(smem + 34816);       // 8*32 f   = 1 KB
        float* invZ  = (float*)(smem + 35840);       // 32 f

        if (tid < 128)
            ((float4*)myp)[tid] = *(const float4*)&pa[((size_t)b*NN + c0)*DPC + tid*4];
        __syncthreads();

        const int cs = tid & 31, jq = tid >> 5;
        float myc[DPC];
        #pragma unroll
        for (int p4 = 0; p4 < 4; ++p4) {
            float4 t = *(const float4*)&myp[cs*DPC + p4*4];
            myc[p4*4+0] = t.x; myc[p4*4+1] = t.y; myc[p4*4+2] = t.z; myc[p4*4+3] = t.w;
        }

        float part = 0.0f;
        for (int h = 0; h < 2; ++h) {
            __syncthreads();
            for (int i = tid; i < 512*DPC/4; i += 256)
                ((float4*)pa_l)[i] = ((const float4*)(pa + ((size_t)b*NN + h*512)*DPC))[i];
            __syncthreads();
            unsigned short* subrow = Sub + ((size_t)b*NN + (c0 + cs))*NN + h*512 + jq*64;
            for (int j4 = 0; j4 < 16; ++j4) {
                float e[4];
                #pragma unroll
                for (int t = 0; t < 4; ++t) {
                    int jj = jq*64 + j4*4 + t;
                    float s = 0.0f;
                    #pragma unroll
                    for (int p4 = 0; p4 < 4; ++p4) {
                        float4 q = *(const float4*)&pa_l[jj*DPC + p4*4];
                        s += fabsf(myc[p4*4+0]-q.x) + fabsf(myc[p4*4+1]-q.y)
                           + fabsf(myc[p4*4+2]-q.z) + fabsf(myc[p4*4+3]-q.w);
                    }
                    e[t] = __expf(-s);
                }
                part += e[0] + e[1] + e[2] + e[3];
                *(ushort4*)&subrow[j4*4] =
                    make_ushort4(f2bf(e[0]), f2bf(e[1]), f2bf(e[2]), f2bf(e[3]));
            }
        }
        zpart[jq*32 + cs] = part;
        __syncthreads();
        // reuse pa_l as xl[32][65]
        float* xl = pa_l;
        #pragma unroll
        for (int i = 0; i < 8; ++i) {
            int l = i*256 + tid, d = l & 63, c = l >> 6;
            xl[c*65 + d] = x[((size_t)b*NN + c0 + c)*DIN + d];
        }
        if (tid < 32) {
            float z = 0.f;
            #pragma unroll
            for (int q = 0; q < 8; ++q) z += zpart[q*32 + tid];
            invZ[tid] = 1.0f / z;
        }
        __syncthreads();
        #pragma unroll
        for (int i = 0; i < 8; ++i) {
            int l = i*256 + tid, c = l & 31, d = l >> 5;
            xzT[((size_t)b*DIN + d)*NN + c0 + c] = f2bf(xl[c*65 + d] * invZ[c]);
        }
    } else if (bid < 1280) {
        // ---------------- sim ----------------
        const int i = bid - 256;
        const int lane = tid & 63, wave = tid >> 6;
        float* redw = (float*)smem;                  // 4 f

        float4 ei0 = *(const float4*)&E[i*EMB + 0];
        float4 ei1 = *(const float4*)&E[i*EMB + 4];
        float4 ei2 = *(const float4*)&E[i*EMB + 8];
        float4 ei3 = *(const float4*)&E[i*EMB + 12];

        float rv[4], tmax = -1e30f;
        #pragma unroll
        for (int k = 0; k < 4; ++k) {
            int j = tid + k*256;
            float4 a0 = *(const float4*)&E[j*EMB + 0];
            float4 a1 = *(const float4*)&E[j*EMB + 4];
            float4 a2 = *(const float4*)&E[j*EMB + 8];
            float4 a3 = *(const float4*)&E[j*EMB + 12];
            float s = ei0.x*a0.x + ei0.y*a0.y + ei0.z*a0.z + ei0.w*a0.w
                    + ei1.x*a1.x + ei1.y*a1.y + ei1.z*a1.z + ei1.w*a1.w
                    + ei2.x*a2.x + ei2.y*a2.y + ei2.z*a2.z + ei2.w*a2.w
                    + ei3.x*a3.x + ei3.y*a3.y + ei3.z*a3.z + ei3.w*a3.w;
            s = fmaxf(s, 0.0f);
            rv[k] = s; tmax = fmaxf(tmax, s);
        }
        #pragma unroll
        for (int off = 32; off > 0; off >>= 1) tmax = fmaxf(tmax, __shfl_xor(tmax, off));
        if (lane == 0) redw[wave] = tmax;
        __syncthreads();
        float rmax = fmaxf(fmaxf(redw[0], redw[1]), fmaxf(redw[2], redw[3]));
        __syncthreads();

        float ev[4], tsum = 0.f;
        #pragma unroll
        for (int k = 0; k < 4; ++k) { ev[k] = __expf(rv[k] - rmax); tsum += ev[k]; }
        #pragma unroll
        for (int off = 32; off > 0; off >>= 1) tsum += __shfl_xor(tsum, off);
        if (lane == 0) redw[wave] = tsum;
        __syncthreads();
        float inv = 1.0f / (redw[0] + redw[1] + redw[2] + redw[3]);
        #pragma unroll
        for (int k = 0; k < 4; ++k)
            sim_bf[(size_t)i*NN + tid + k*256] = f2bf(ev[k] * inv);
    } else {
        // ---------------- pack: WPT[col=d*64+o][ki=k*64+i] = bf16(wp[d][k][i][o]) ----------------
        const int d = bid - 1280;
        float* wpl = (float*)smem;                   // 8192 f = 32 KB
        const float* wsrc = wp + (size_t)d * 8192;
        for (int i = tid; i < 2048; i += 256)
            ((float4*)wpl)[i] = ((const float4*)wsrc)[i];
        __syncthreads();
        const int o = tid & 63, g = tid >> 6;        // g: i-quarter
        #pragma unroll
        for (int k = 0; k < 2; ++k) {
            unsigned short tmp[16];
            #pragma unroll
            for (int t = 0; t < 16; ++t)
                tmp[t] = f2bf(wpl[k*4096 + (g*16 + t)*64 + o]);
            unsigned short* dst = WPT + (size_t)(d*64 + o)*128 + k*64 + g*16;
            #pragma unroll
            for (int t4 = 0; t4 < 4; ++t4)
                *(ushort4*)&dst[t4*4] =
                    make_ushort4(tmp[t4*4], tmp[t4*4+1], tmp[t4*4+2], tmp[t4*4+3]);
        }
    }
}

// =======================================================================
// bf16 GEMM tile, BM=32: C[32m x 64d] = A[32m x 1024k] * B^T[64d x 1024k]
// K-step 64, register prefetch, single LDS buffer. 4 waves: wave w owns
// d-cols w*16..w*16+15 for BOTH 16-row groups. 16 MFMA per block per
// K-step against 2 barriers (2x the old BM=16 amortization).
// =======================================================================
#define ASTR 72
#define BSTR 72

__device__ inline void gemm_tile32(const unsigned short* __restrict__ Arow,  // A[r][c] = Arow[r*NN+c]
                                   const unsigned short* __restrict__ Brow,  // B[d][c] = Brow[d*NN+c]
                                   unsigned short* A_l, unsigned short* B_l,
                                   int tid, f32x4& acc0, f32x4& acc1) {
    const int lane = tid & 63, wave = tid >> 6;
    const int q = lane >> 4, r = lane & 15;

    const int brow_ = tid >> 2, bch = (tid & 3) * 2;   // B: 64 rows x 64 cols
    const int arow_ = tid >> 3, ach = tid & 7;         // A: 32 rows x 64 cols

    uint4 pb0 = *(const uint4*)&Brow[(size_t)brow_*NN + (bch+0)*8];
    uint4 pb1 = *(const uint4*)&Brow[(size_t)brow_*NN + (bch+1)*8];
    uint4 pa0 = *(const uint4*)&Arow[(size_t)arow_*NN + ach*8];

    for (int kk = 0; kk < 16; ++kk) {
        __syncthreads();
        *(uint4*)&B_l[brow_*BSTR + (bch+0)*8] = pb0;
        *(uint4*)&B_l[brow_*BSTR + (bch+1)*8] = pb1;
        *(uint4*)&A_l[arow_*ASTR + ach*8] = pa0;
        __syncthreads();
        if (kk < 15) {
            int c1 = (kk + 1) * 64;
            pb0 = *(const uint4*)&Brow[(size_t)brow_*NN + c1 + (bch+0)*8];
            pb1 = *(const uint4*)&Brow[(size_t)brow_*NN + c1 + (bch+1)*8];
            pa0 = *(const uint4*)&Arow[(size_t)arow_*NN + c1 + ach*8];
        }
        #pragma unroll
        for (int ks = 0; ks < 2; ++ks) {
            bf16x8 bfr = *(const bf16x8*)&B_l[(wave*16 + r)*BSTR + ks*32 + q*8];
            bf16x8 a0 = *(const bf16x8*)&A_l[r*ASTR + ks*32 + q*8];
            acc0 = __builtin_amdgcn_mfma_f32_16x16x32_bf16(a0, bfr, acc0, 0, 0, 0);
            bf16x8 a1 = *(const bf16x8*)&A_l[(16 + r)*ASTR + ks*32 + q*8];
            acc1 = __builtin_amdgcn_mfma_f32_16x16x32_bf16(a1, bfr, acc1, 0, 0, 0);
        }
    }
}

// ---------------- k_sx4: sx = Sub(m-rows) @ xz ; emits sx_bf + sxT (both bf16) ----------------
__global__ __launch_bounds__(256) void k_sx4(const unsigned short* __restrict__ Sub,
                                             const unsigned short* __restrict__ xzT,
                                             unsigned short* __restrict__ sx_bf,
                                             unsigned short* __restrict__ sxT) {
    const int b = blockIdx.y, m0 = blockIdx.x * 32;
    const int tid = threadIdx.x, lane = tid & 63, wave = tid >> 6;
    __shared__ __align__(16) unsigned short A_l[32 * ASTR];
    __shared__ __align__(16) unsigned short B_l[64 * BSTR];

    f32x4 acc0 = {0.f, 0.f, 0.f, 0.f}, acc1 = {0.f, 0.f, 0.f, 0.f};
    gemm_tile32(Sub + ((size_t)b*NN + m0)*NN, xzT + (size_t)b*DIN*NN, A_l, B_l, tid, acc0, acc1);

    const int q = lane >> 4, r = lane & 15;
    const int d = wave*16 + r;
    #pragma unroll
    for (int rt = 0; rt < 2; ++rt) {
        const f32x4& acc = rt ? acc1 : acc0;
        const int mrow = m0 + rt*16 + q*4;
        unsigned short h0 = f2bf(acc[0]), h1 = f2bf(acc[1]), h2 = f2bf(acc[2]), h3 = f2bf(acc[3]);
        sx_bf[((size_t)b*NN + mrow + 0)*DIN + d] = h0;
        sx_bf[((size_t)b*NN + mrow + 1)*DIN + d] = h1;
        sx_bf[((size_t)b*NN + mrow + 2)*DIN + d] = h2;
        sx_bf[((size_t)b*NN + mrow + 3)*DIN + d] = h3;
        *(ushort4*)&sxT[((size_t)b*DIN + d)*NN + mrow] = make_ushort4(h0, h1, h2, h3);
    }
}

// =======================================================================
// k_y_out (BM=32): y = sim_bf(m-rows) @ sx (B from sxT), then in-block:
//   P[row, d*64+o] = sum_ki [sx_bf | y][row,ki] * WPT[d*64+o][ki]   (MFMA, K=128)
//   out[row,o]     = sum_d E[n,d] * P[row,d*64+o] + sum_d E[n,d]*bp[d,o]
// Each WPT B-fragment is loaded ONCE and used for both 16-row groups
// (halves WPT L2 traffic vs BM=16).
// =======================================================================
#define S2 136          // A2 row stride (u16): 128 data + 8 pad
#define PSTR 65         // partials row stride (f32)

__global__ __launch_bounds__(256) void k_y_out(const unsigned short* __restrict__ sim_bf,
                                               const unsigned short* __restrict__ sxT,
                                               const unsigned short* __restrict__ sx_bf,
                                               const unsigned short* __restrict__ WPT,
                                               const float* __restrict__ E,
                                               const float* __restrict__ bp,
                                               float* __restrict__ out) {
    const int b = blockIdx.y, m0 = blockIdx.x * 32;
    const int tid = threadIdx.x, lane = tid & 63, wave = tid >> 6;
    __shared__ __align__(16) unsigned short A_l[32 * ASTR];    //  4.5 KB
    __shared__ __align__(16) unsigned short B_l[64 * BSTR];    //  9.0 KB
    __shared__ __align__(16) unsigned short A2[32 * S2];       //  8.5 KB [row][ki]: 0..63 sx, 64..127 y
    __shared__ float E32[32 * EMB];                            //  2.0 KB
    __shared__ float bpl[EMB * DOUT];                          //  4.0 KB
    __shared__ float part[4 * 32 * PSTR];                      // 32.5 KB per-wave d-partials

    // stage epilogue inputs early (ordered by the barriers inside gemm_tile32)
    if (tid < 128)
        ((float4*)E32)[tid] = ((const float4*)&E[(size_t)m0 * EMB])[tid];  // 512 f32
    ((float4*)bpl)[tid] = ((const float4*)bp)[tid];                        // 1024 f32
    {                                                                      // sx half of A2
        int row = tid >> 3, c8 = (tid & 7) * 8;
        *(uint4*)&A2[row*S2 + c8] =
            *(const uint4*)&sx_bf[((size_t)b*NN + m0 + row)*DIN + c8];
    }

    f32x4 acc0 = {0.f, 0.f, 0.f, 0.f}, acc1 = {0.f, 0.f, 0.f, 0.f};
    gemm_tile32(sim_bf + (size_t)m0*NN, sxT + (size_t)b*DIN*NN, A_l, B_l, tid, acc0, acc1);

    const int q = lane >> 4, r = lane & 15;
    // y halves of A2: wave owns cols wave*16+r, rows rt*16 + q*4 + reg
    #pragma unroll
    for (int reg = 0; reg < 4; ++reg)
        A2[(q*4 + reg)*S2 + 64 + wave*16 + r] = f2bf(acc0[reg]);
    #pragma unroll
    for (int reg = 0; reg < 4; ++reg)
        A2[(16 + q*4 + reg)*S2 + 64 + wave*16 + r] = f2bf(acc1[reg]);
    __syncthreads();

    // ---- P-GEMM: [32 x 128] @ [128 x 1024], wave w owns cols w*256..w*256+255 ----
    bf16x8 af[2][4];
    #pragma unroll
    for (int rt = 0; rt < 2; ++rt)
        #pragma unroll
        for (int ks = 0; ks < 4; ++ks)
            af[rt][ks] = *(const bf16x8*)&A2[(rt*16 + r)*S2 + ks*32 + q*8];

    f32x4 pacc[2][16];
    #pragma unroll
    for (int rt = 0; rt < 2; ++rt)
        #pragma unroll
        for (int i = 0; i < 16; ++i) pacc[rt][i] = (f32x4){0.f, 0.f, 0.f, 0.f};

    const unsigned short* wbase = WPT + ((size_t)(wave*256 + r))*128 + q*8;
    #pragma unroll
    for (int nfl = 0; nfl < 16; ++nfl) {
        const unsigned short* bb = wbase + (size_t)nfl * 16 * 128;
        #pragma unroll
        for (int ks = 0; ks < 4; ++ks) {
            bf16x8 bf_ = *(const bf16x8*)(bb + ks*32);
            pacc[0][nfl] = __builtin_amdgcn_mfma_f32_16x16x32_bf16(af[0][ks], bf_, pacc[0][nfl], 0, 0, 0);
            pacc[1][nfl] = __builtin_amdgcn_mfma_f32_16x16x32_bf16(af[1][ks], bf_, pacc[1][nfl], 0, 0, 0);
        }
    }

    // ---- contract with E over this wave's 4 d-values ----
    // col = wave*256 + nfl*16 + r  ->  d = wave*4 + (nfl>>2), o = (nfl&3)*16 + r
    float po[2][4][4];
    #pragma unroll
    for (int rt = 0; rt < 2; ++rt)
        #pragma unroll
        for (int reg = 0; reg < 4; ++reg)
            #pragma unroll
            for (int ohi = 0; ohi < 4; ++ohi) po[rt][reg][ohi] = 0.f;
    #pragma unroll
    for (int nfl = 0; nfl < 16; ++nfl) {
        const int dd = nfl >> 2, ohi = nfl & 3;
        #pragma unroll
        for (int rt = 0; rt < 2; ++rt)
            #pragma unroll
            for (int reg = 0; reg < 4; ++reg)
                po[rt][reg][ohi] += E32[(rt*16 + q*4 + reg)*EMB + wave*4 + dd] * pacc[rt][nfl][reg];
    }
    #pragma unroll
    for (int rt = 0; rt < 2; ++rt)
        #pragma unroll
        for (int reg = 0; reg < 4; ++reg)
            #pragma unroll
            for (int ohi = 0; ohi < 4; ++ohi)
                part[wave*32*PSTR + (rt*16 + q*4 + reg)*PSTR + ohi*16 + r] = po[rt][reg][ohi];
    __syncthreads();

    // ---- reduce 4 waves (4 d-groups each) + bias, write out ----
    #pragma unroll
    for (int g = 0; g < 2; ++g) {
        const int idx = g*256 + tid;
        const int row = idx >> 4, o4 = (idx & 15) * 4;
        float4 res;
        #pragma unroll
        for (int j = 0; j < 4; ++j) {
            const int o = o4 + j;
            float s = part[0*32*PSTR + row*PSTR + o] + part[1*32*PSTR + row*PSTR + o]
                    + part[2*32*PSTR + row*PSTR + o] + part[3*32*PSTR + row*PSTR + o];
            float bsum = 0.f;
            #pragma unroll
            for (int d = 0; d < EMB; ++d)
                bsum += E32[row*EMB + d] * bpl[d*DOUT + o];
            ((float*)&res)[j] = s + bsum;
        }
        *(float4*)&out[((size_t)b*NN + m0 + row)*DOUT + o4] = res;
    }
}

extern "C" void kernel_launch(void* const* d_in, const int* in_sizes, int n_in,
                              void* d_out, int out_size, void* d_ws, size_t ws_size,
                              hipStream_t stream) {
    (void)in_sizes; (void)n_in; (void)out_size; (void)ws_size;
    const float* x  = (const float*)d_in[0];
    const float* E  = (const float*)d_in[1];
    const float* pa = (const float*)d_in[2];
    const float* wp = (const float*)d_in[3];
    const float* bp = (const float*)d_in[4];
    float* out = (float*)d_out;

    // ws layout (~21.3 MiB used)
    unsigned short* ws16   = (unsigned short*)d_ws;
    unsigned short* sim_bf = ws16;                       // 1,048,576 us (2 MiB)
    unsigned short* xzT    = sim_bf + (size_t)NN*NN;     //   524,288 us (1 MiB)
    unsigned short* sxT    = xzT + (size_t)BB*DIN*NN;    //   524,288 us (1 MiB)
    unsigned short* Sub    = sxT + (size_t)BB*DIN*NN;    // 8,388,608 us (16 MiB)
    unsigned short* sx_bf  = Sub + (size_t)BB*NN*NN;     //   524,288 us (1 MiB)
    unsigned short* WPT    = sx_bf + (size_t)BB*NN*DIN;  //   131,072 us (256 KiB)

    k_front<<<1296, 256, 0, stream>>>(E, pa, x, wp, sim_bf, Sub, xzT, WPT);
    k_sx4<<<dim3(32, BB), 256, 0, stream>>>(Sub, xzT, sx_bf, sxT);
    k_y_out<<<dim3(32, BB), 256, 0, stream>>>(sim_bf, sxT, sx_bf, WPT, E, bp, out);
}